// Round 1
// baseline (1561.804 us; speedup 1.0000x reference)
//
#include <hip/hip_runtime.h>

// ---------------- types / helpers ----------------
typedef __bf16 bf16x8 __attribute__((ext_vector_type(8)));
typedef float  f32x4  __attribute__((ext_vector_type(4)));
typedef unsigned short ushort8v __attribute__((ext_vector_type(8)));

#define DEV __device__ __forceinline__

constexpr int Dm = 4096;   // model dim
constexpr int Sq = 2048;   // seq len
constexpr int Bb = 2;      // batch
constexpr int Hh = 32;     // heads
constexpr int HDd = 128;   // head dim

DEV unsigned short f2bf(float f) {
  union { float f; unsigned u; } v; v.f = f;
  unsigned u = v.u;
  return (unsigned short)((u + 0x7fffu + ((u >> 16) & 1u)) >> 16); // RNE
}
DEV float bf2f(unsigned short s) {
  union { unsigned u; float f; } v; v.u = ((unsigned)s) << 16;
  return v.f;
}

// ---------------- cast fp32 -> bf16, 8 elems/thread ----------------
__global__ __launch_bounds__(256) void cast_f32_bf16(const float* __restrict__ src,
                                                     unsigned short* __restrict__ dst,
                                                     int n8) {
  int i = blockIdx.x * 256 + threadIdx.x;
  if (i >= n8) return;
  const float4* s4 = (const float4*)src;
  float4 a = s4[2 * i], b = s4[2 * i + 1];
  ushort8v o;
  o[0] = f2bf(a.x); o[1] = f2bf(a.y); o[2] = f2bf(a.z); o[3] = f2bf(a.w);
  o[4] = f2bf(b.x); o[5] = f2bf(b.y); o[6] = f2bf(b.z); o[7] = f2bf(b.w);
  *(ushort8v*)(dst + 8 * i) = o;
}

// ---------------- RoPE cos/sin tables [S][64] ----------------
__global__ __launch_bounds__(256) void rope_tables(float* __restrict__ cosT,
                                                   float* __restrict__ sinT) {
  int idx = blockIdx.x * 256 + threadIdx.x;  // S*64 = 131072
  int s = idx >> 6, i = idx & 63;
  // inv_freq = 10000^(-i/64) = exp(-i * ln(10000)/64)
  float inv = expf(-(float)i * (9.210340371976184f / 64.0f));
  float f = (float)s * inv;
  cosT[idx] = cosf(f);
  sinT[idx] = sinf(f);
}

// ---------------- GEMM C[m,n] = sum_k A[m,k]*B[n,k]  (both K-contiguous) ----
// 128x128 tile, BK=64, 4 waves (2x2 of 64x64), 16x16x32 bf16 MFMA.
// LDS XOR-swizzle (row&7)<<4 on 16B chunks: conflict-free ds_read_b128.
template <int WF32>
__global__ __launch_bounds__(256) void gemm_nt(const unsigned short* __restrict__ A,
                                               const unsigned short* __restrict__ Bw,
                                               unsigned short* __restrict__ Cb,
                                               float* __restrict__ Cf, int K) {
  constexpr int TM = 128, BK = 64;
  __shared__ unsigned short lA[TM * BK];
  __shared__ unsigned short lB[TM * BK];
  const int tid = threadIdx.x;
  const int l = tid & 63, w = tid >> 6;
  const int wm = (w >> 1) * 64, wn = (w & 1) * 64;
  const int m0 = blockIdx.x * TM, n0 = blockIdx.y * TM;
  f32x4 acc[4][4] = {};

  const int scb = (tid & 7) * 16;  // byte col within 128B row
  const unsigned short* Ag = A + (size_t)m0 * K;
  const unsigned short* Bg = Bw + (size_t)n0 * K;

  for (int k0 = 0; k0 < K; k0 += BK) {
    __syncthreads();
#pragma unroll
    for (int i = 0; i < 4; i++) {
      int row = (tid >> 3) + 32 * i;
      uint4 va = *(const uint4*)((const char*)Ag + ((size_t)row * K + k0) * 2 + scb);
      uint4 vb = *(const uint4*)((const char*)Bg + ((size_t)row * K + k0) * 2 + scb);
      int lo = row * 128 + (scb ^ ((row & 7) << 4));
      *(uint4*)((char*)lA + lo) = va;
      *(uint4*)((char*)lB + lo) = vb;
    }
    __syncthreads();
#pragma unroll
    for (int kc = 0; kc < 2; kc++) {
      bf16x8 af[4], bfr[4];
#pragma unroll
      for (int mi = 0; mi < 4; mi++) {
        int row = wm + mi * 16 + (l & 15);
        int cb = (kc * 64 + (l >> 4) * 16) ^ ((row & 7) << 4);
        af[mi] = *(const bf16x8*)((const char*)lA + row * 128 + cb);
      }
#pragma unroll
      for (int ni = 0; ni < 4; ni++) {
        int row = wn + ni * 16 + (l & 15);
        int cb = (kc * 64 + (l >> 4) * 16) ^ ((row & 7) << 4);
        bfr[ni] = *(const bf16x8*)((const char*)lB + row * 128 + cb);
      }
#pragma unroll
      for (int mi = 0; mi < 4; mi++)
#pragma unroll
        for (int ni = 0; ni < 4; ni++)
          acc[mi][ni] = __builtin_amdgcn_mfma_f32_16x16x32_bf16(af[mi], bfr[ni], acc[mi][ni], 0, 0, 0);
    }
  }
  // epilogue: C row = (l>>4)*4 + r, col = l&15 (verified m89/m91 layout)
#pragma unroll
  for (int mi = 0; mi < 4; mi++) {
    int mrow = m0 + wm + mi * 16 + (l >> 4) * 4;
#pragma unroll
    for (int ni = 0; ni < 4; ni++) {
      int ncol = n0 + wn + ni * 16 + (l & 15);
#pragma unroll
      for (int r = 0; r < 4; r++) {
        if constexpr (WF32)
          Cf[(size_t)(mrow + r) * Dm + ncol] = acc[mi][ni][r];
        else
          Cb[(size_t)(mrow + r) * Dm + ncol] = f2bf(acc[mi][ni][r]);
      }
    }
  }
}

// ---------------- RoPE in-place on Q,K [4096][4096] bf16 ----------------
__global__ __launch_bounds__(256) void rope_apply(unsigned short* __restrict__ Q,
                                                  unsigned short* __restrict__ Kt,
                                                  const float* __restrict__ cosT,
                                                  const float* __restrict__ sinT) {
  int idx = blockIdx.x * 256 + threadIdx.x;  // 1,048,576 threads
  unsigned short* P = blockIdx.y ? Kt : Q;
  int j = idx & 7;
  int h = (idx >> 3) & 31;
  int m = idx >> 8;
  int s = m & (Sq - 1);
  size_t base = (size_t)m * Dm + h * HDd + j * 8;
  ushort8v u1 = *(ushort8v*)(P + base);
  ushort8v u2 = *(ushort8v*)(P + base + 64);
  const float* cp = cosT + s * 64 + j * 8;
  const float* sp = sinT + s * 64 + j * 8;
  ushort8v o1, o2;
#pragma unroll
  for (int e = 0; e < 8; e++) {
    float c = cp[e], sn = sp[e];
    float x1 = bf2f(u1[e]), x2 = bf2f(u2[e]);
    o1[e] = f2bf(x1 * c - x2 * sn);
    o2[e] = f2bf(x2 * c + x1 * sn);
  }
  *(ushort8v*)(P + base) = o1;
  *(ushort8v*)(P + base + 64) = o2;
}

// ---------------- V [m][4096] -> VT [(b*H+h)*128 + hd][2048] ----------------
__global__ __launch_bounds__(256) void transpose_v(const unsigned short* __restrict__ V,
                                                   unsigned short* __restrict__ VT) {
  __shared__ unsigned short t[32][33];
  int bh = blockIdx.z;
  int s0 = blockIdx.x * 32, d0 = blockIdx.y * 32;
  int tx = threadIdx.x, ty = threadIdx.y;  // (32,8)
  int b = bh >> 5, h = bh & 31;
#pragma unroll
  for (int i = 0; i < 4; i++) {
    int row = ty + i * 8;
    t[row][tx] = V[((size_t)(b * Sq + s0 + row)) * Dm + h * HDd + d0 + tx];
  }
  __syncthreads();
#pragma unroll
  for (int i = 0; i < 4; i++) {
    int row = ty + i * 8;
    VT[((size_t)bh * HDd + d0 + row) * Sq + s0 + tx] = t[tx][row];
  }
}

// ---------------- flash attention, causal, QB=64 KVB=64, 4 waves ----------
__global__ __launch_bounds__(256) void flash_attn(const unsigned short* __restrict__ Qg,
                                                  const unsigned short* __restrict__ Kg,
                                                  const unsigned short* __restrict__ VTg,
                                                  unsigned short* __restrict__ Ctx) {
  constexpr int QB = 64, KVB = 64, PP = 88;  // PP = P LDS pitch (16B aligned)
  __shared__ unsigned short lK[KVB * HDd];   // [64][128] swizzled
  __shared__ unsigned short lV[HDd * KVB];   // [128][64] swizzled (V^T)
  __shared__ unsigned short lP[4][16 * PP];  // per-wave P tile
  const int tid = threadIdx.x, l = tid & 63, w = tid >> 6;
  const int q0 = blockIdx.x * QB;
  const int bh = blockIdx.y, b = bh >> 5, h = bh & 31;

  // Q fragments (A operand): row = l&15, k = 8*(l>>4)+e, 4 chunks of K=32
  bf16x8 qf[4];
  {
    int qrow = q0 + w * 16 + (l & 15);
    const unsigned short* qp = Qg + ((size_t)(b * Sq + qrow)) * Dm + h * HDd + (l >> 4) * 8;
#pragma unroll
    for (int c = 0; c < 4; c++) qf[c] = *(const bf16x8*)(qp + c * 32);
  }

  f32x4 acc[8] = {};
  float mrun[4] = {-1e30f, -1e30f, -1e30f, -1e30f};
  float lrun[4] = {0.f, 0.f, 0.f, 0.f};
  const float scale = 0.08838834764831845f;  // 1/sqrt(128)
  const float L2E = 1.4426950408889634f;

  const int ntile = blockIdx.x + 1;  // causal: kv tiles 0..q0/64
  for (int t = 0; t < ntile; t++) {
    int kv0 = t * KVB;
    __syncthreads();
    // stage K tile [64][128], 16B chunks, swizzled
#pragma unroll
    for (int i = 0; i < 4; i++) {
      int c = tid + 256 * i;
      int row = c >> 4, cb = (c & 15) * 16;
      uint4 vd = *(const uint4*)((const char*)Kg +
                                 (((size_t)(b * Sq + kv0 + row)) * Dm + h * HDd) * 2 + cb);
      *(uint4*)((char*)lK + row * 256 + (cb ^ ((row & 7) << 4))) = vd;
    }
    // stage V^T tile [128][64]
#pragma unroll
    for (int i = 0; i < 4; i++) {
      int c = tid + 256 * i;
      int row = c >> 3, cb = (c & 7) * 16;
      uint4 vd = *(const uint4*)((const char*)VTg +
                                 (((size_t)(bh * HDd + row)) * Sq + kv0) * 2 + cb);
      *(uint4*)((char*)lV + row * 128 + (cb ^ ((row & 7) << 4))) = vd;
    }
    __syncthreads();

    // QK^T: scores[16q x 64kv] per wave
    f32x4 sc[4] = {};
#pragma unroll
    for (int nb = 0; nb < 4; nb++) {
      int kvr = nb * 16 + (l & 15);
#pragma unroll
      for (int c = 0; c < 4; c++) {
        int cb = (c * 64 + (l >> 4) * 16) ^ ((kvr & 7) << 4);
        bf16x8 kf = *(const bf16x8*)((const char*)lK + kvr * 256 + cb);
        sc[nb] = __builtin_amdgcn_mfma_f32_16x16x32_bf16(qf[c], kf, sc[nb], 0, 0, 0);
      }
    }

    // scale + causal mask
    float sv[4][4];
#pragma unroll
    for (int nb = 0; nb < 4; nb++) {
      int kvg = kv0 + nb * 16 + (l & 15);
#pragma unroll
      for (int r = 0; r < 4; r++) {
        int qg = q0 + w * 16 + (l >> 4) * 4 + r;
        float vv = sc[nb][r] * scale;
        sv[nb][r] = (kvg <= qg) ? vv : -1e30f;
      }
    }
    // row max over 16 cols (lanes l&15), wave-parallel
    float rmax[4];
#pragma unroll
    for (int r = 0; r < 4; r++)
      rmax[r] = fmaxf(fmaxf(sv[0][r], sv[1][r]), fmaxf(sv[2][r], sv[3][r]));
#pragma unroll
    for (int d = 1; d < 16; d <<= 1)
#pragma unroll
      for (int r = 0; r < 4; r++) rmax[r] = fmaxf(rmax[r], __shfl_xor(rmax[r], d, 64));

    float mnew[4], alpha[4], psum[4];
#pragma unroll
    for (int r = 0; r < 4; r++) {
      mnew[r] = fmaxf(mrun[r], rmax[r]);
      alpha[r] = exp2f((mrun[r] - mnew[r]) * L2E);
      psum[r] = 0.f;
    }
    float pvv[4][4];
#pragma unroll
    for (int nb = 0; nb < 4; nb++)
#pragma unroll
      for (int r = 0; r < 4; r++) {
        float pe = exp2f((sv[nb][r] - mnew[r]) * L2E);
        pvv[nb][r] = pe;
        psum[r] += pe;
      }
#pragma unroll
    for (int d = 1; d < 16; d <<= 1)
#pragma unroll
      for (int r = 0; r < 4; r++) psum[r] += __shfl_xor(psum[r], d, 64);
#pragma unroll
    for (int r = 0; r < 4; r++) {
      lrun[r] = lrun[r] * alpha[r] + psum[r];
      mrun[r] = mnew[r];
    }
#pragma unroll
    for (int hdnb = 0; hdnb < 8; hdnb++)
#pragma unroll
      for (int r = 0; r < 4; r++) acc[hdnb][r] *= alpha[r];

    // P -> per-wave LDS tile [16][PP]
    unsigned short* P = lP[w];
#pragma unroll
    for (int nb = 0; nb < 4; nb++)
#pragma unroll
      for (int r = 0; r < 4; r++)
        P[((l >> 4) * 4 + r) * PP + nb * 16 + (l & 15)] = f2bf(pvv[nb][r]);

    // PV: A = P[16q x 64kv], B = V[64kv x 128hd] from swizzled V^T LDS
    bf16x8 pf[2];
#pragma unroll
    for (int kc = 0; kc < 2; kc++)
      pf[kc] = *(const bf16x8*)(P + (l & 15) * PP + kc * 32 + (l >> 4) * 8);
#pragma unroll
    for (int hdnb = 0; hdnb < 8; hdnb++) {
      int hdr = hdnb * 16 + (l & 15);
#pragma unroll
      for (int kc = 0; kc < 2; kc++) {
        int cb = (kc * 64 + (l >> 4) * 16) ^ ((hdr & 7) << 4);
        bf16x8 vf = *(const bf16x8*)((const char*)lV + hdr * 128 + cb);
        acc[hdnb] = __builtin_amdgcn_mfma_f32_16x16x32_bf16(pf[kc], vf, acc[hdnb], 0, 0, 0);
      }
    }
  }

  // epilogue: ctx[m][h*128+hd] bf16
  float invl[4];
#pragma unroll
  for (int r = 0; r < 4; r++) invl[r] = 1.0f / lrun[r];
#pragma unroll
  for (int hdnb = 0; hdnb < 8; hdnb++)
#pragma unroll
    for (int r = 0; r < 4; r++) {
      size_t mrow = (size_t)(b * Sq + q0 + w * 16 + (l >> 4) * 4 + r);
      Ctx[mrow * Dm + h * HDd + hdnb * 16 + (l & 15)] = f2bf(acc[hdnb][r] * invl[r]);
    }
}

// ---------------- launch ----------------
extern "C" void kernel_launch(void* const* d_in, const int* in_sizes, int n_in,
                              void* d_out, int out_size, void* d_ws, size_t ws_size,
                              hipStream_t stream) {
  (void)in_sizes; (void)n_in; (void)out_size; (void)ws_size;
  const float* x  = (const float*)d_in[0];
  // d_in[1] = mask (causal tril) — hardcoded in flash kernel
  const float* Wq = (const float*)d_in[2];
  const float* Wk = (const float*)d_in[3];
  const float* Wv = (const float*)d_in[4];
  const float* Wo = (const float*)d_in[5];
  float* out = (float*)d_out;

  char* p = (char*)d_ws;
  const size_t TB = (size_t)Dm * Dm * 2;  // 32 MiB per bf16 4096x4096 tensor
  unsigned short* xb = (unsigned short*)p; p += TB;  // also reused as VT
  unsigned short* wq = (unsigned short*)p; p += TB;
  unsigned short* wk = (unsigned short*)p; p += TB;
  unsigned short* wv = (unsigned short*)p; p += TB;
  unsigned short* wo = (unsigned short*)p; p += TB;
  unsigned short* qb = (unsigned short*)p; p += TB;
  unsigned short* kb = (unsigned short*)p; p += TB;
  unsigned short* vb = (unsigned short*)p; p += TB;  // also reused as ctx
  float* cosT = (float*)p; p += (size_t)Sq * 64 * 4;
  float* sinT = (float*)p; p += (size_t)Sq * 64 * 4;
  unsigned short* vT  = xb;  // x bf16 dead after the 3 projection GEMMs
  unsigned short* ctx = vb;  // v bf16 dead after transpose

  const int n8 = Dm * Dm / 8;      // 2,097,152
  const int castBlocks = n8 / 256; // 8192

  cast_f32_bf16<<<castBlocks, 256, 0, stream>>>(x, xb, n8);
  cast_f32_bf16<<<castBlocks, 256, 0, stream>>>(Wq, wq, n8);
  cast_f32_bf16<<<castBlocks, 256, 0, stream>>>(Wk, wk, n8);
  cast_f32_bf16<<<castBlocks, 256, 0, stream>>>(Wv, wv, n8);
  cast_f32_bf16<<<castBlocks, 256, 0, stream>>>(Wo, wo, n8);
  rope_tables<<<512, 256, 0, stream>>>(cosT, sinT);

  dim3 gg(32, 32);
  gemm_nt<0><<<gg, 256, 0, stream>>>(xb, wq, qb, nullptr, Dm);
  gemm_nt<0><<<gg, 256, 0, stream>>>(xb, wk, kb, nullptr, Dm);
  gemm_nt<0><<<gg, 256, 0, stream>>>(xb, wv, vb, nullptr, Dm);

  rope_apply<<<dim3(4096, 2), 256, 0, stream>>>(qb, kb, cosT, sinT);
  transpose_v<<<dim3(64, 4, 64), dim3(32, 8), 0, stream>>>(vb, vT);

  flash_attn<<<dim3(Sq / 64, Bb * Hh), 256, 0, stream>>>(qb, kb, vT, ctx);

  gemm_nt<1><<<gg, 256, 0, stream>>>(ctx, wo, nullptr, out, Dm);
}

// Round 3
// 1547.331 us; speedup vs baseline: 1.0094x; 1.0094x over previous
//
#include <hip/hip_runtime.h>

// ---------------- types / helpers ----------------
typedef __bf16 bf16x8 __attribute__((ext_vector_type(8)));
typedef float  f32x4  __attribute__((ext_vector_type(4)));
typedef unsigned short ushort8v __attribute__((ext_vector_type(8)));

#define DEV __device__ __forceinline__

constexpr int Dm = 4096;   // model dim
constexpr int Sq = 2048;   // seq len
constexpr int Bb = 2;      // batch
constexpr int Hh = 32;     // heads
constexpr int HDd = 128;   // head dim

DEV unsigned short f2bf(float f) {
  union { float f; unsigned u; } v; v.f = f;
  unsigned u = v.u;
  return (unsigned short)((u + 0x7fffu + ((u >> 16) & 1u)) >> 16); // RNE
}
DEV float bf2f(unsigned short s) {
  union { unsigned u; float f; } v; v.u = ((unsigned)s) << 16;
  return v.f;
}

// ---------------- cast fp32 -> bf16, 8 elems/thread ----------------
__global__ __launch_bounds__(256) void cast_f32_bf16(const float* __restrict__ src,
                                                     unsigned short* __restrict__ dst,
                                                     int n8) {
  int i = blockIdx.x * 256 + threadIdx.x;
  if (i >= n8) return;
  const float4* s4 = (const float4*)src;
  float4 a = s4[2 * i], b = s4[2 * i + 1];
  ushort8v o;
  o[0] = f2bf(a.x); o[1] = f2bf(a.y); o[2] = f2bf(a.z); o[3] = f2bf(a.w);
  o[4] = f2bf(b.x); o[5] = f2bf(b.y); o[6] = f2bf(b.z); o[7] = f2bf(b.w);
  *(ushort8v*)(dst + 8 * i) = o;
}

// ---------------- RoPE cos/sin tables [S][64] ----------------
__global__ __launch_bounds__(256) void rope_tables(float* __restrict__ cosT,
                                                   float* __restrict__ sinT) {
  int idx = blockIdx.x * 256 + threadIdx.x;  // S*64 = 131072
  int s = idx >> 6, i = idx & 63;
  float inv = expf(-(float)i * (9.210340371976184f / 64.0f));
  float f = (float)s * inv;
  cosT[idx] = cosf(f);
  sinT[idx] = sinf(f);
}

// ---------------- GEMM C[m,n] = sum_k A[m,k]*B[n,k]  (m97 structure) ------
// 128x128 tile, BK=64, 4 waves (2x2 of 64x64), 16x16x32 bf16 MFMA.
// global_load_lds width=16 staging into LINEAR LDS (swizzle is null at this
// 2-barrier structure per T2 regime gate; m97 measured 874-912 TF).
template <int WF32>
__global__ __launch_bounds__(256) void gemm_nt(const unsigned short* __restrict__ A,
                                               const unsigned short* __restrict__ Bw,
                                               unsigned short* __restrict__ Cb,
                                               float* __restrict__ Cf, int K) {
  constexpr int TM = 128, BK = 64;
  __shared__ unsigned short lA[TM * BK];
  __shared__ unsigned short lB[TM * BK];
  const int tid = threadIdx.x;
  const int l = tid & 63, w = tid >> 6;
  const int wm = (w >> 1) * 64, wn = (w & 1) * 64;
  const int m0 = blockIdx.x * TM, n0 = blockIdx.y * TM;
  f32x4 acc[4][4] = {};

  const unsigned short* Ag = A + (size_t)m0 * K;
  const unsigned short* Bg = Bw + (size_t)n0 * K;
  const int srow = l >> 3;        // row within 8-row chunk
  const int scb = (l & 7) * 16;   // byte col within 128B row

  for (int k0 = 0; k0 < K; k0 += BK) {
    __syncthreads();
    // wave w stages rows w*32 .. w*32+31 of A and B: 4 instrs x 8 rows x 1KB.
    // LDS dest wave-uniform base; lane l lands at base + l*16 (linear order).
#pragma unroll
    for (int i = 0; i < 4; i++) {
      int row = w * 32 + i * 8 + srow;
      __builtin_amdgcn_global_load_lds(
          (const __attribute__((address_space(1))) void*)((const char*)Ag +
              ((size_t)row * K + k0) * 2 + scb),
          (__attribute__((address_space(3))) void*)(lA + (w * 4 + i) * 512),
          16, 0, 0);
      __builtin_amdgcn_global_load_lds(
          (const __attribute__((address_space(1))) void*)((const char*)Bg +
              ((size_t)row * K + k0) * 2 + scb),
          (__attribute__((address_space(3))) void*)(lB + (w * 4 + i) * 512),
          16, 0, 0);
    }
    __syncthreads();  // compiler emits vmcnt(0) drain -> LDS tile ready
#pragma unroll
    for (int kc = 0; kc < 2; kc++) {
      bf16x8 af[4], bfr[4];
#pragma unroll
      for (int mi = 0; mi < 4; mi++)
        af[mi] = *(const bf16x8*)((const char*)lA +
                                  (wm + mi * 16 + (l & 15)) * 128 + kc * 64 + (l >> 4) * 16);
#pragma unroll
      for (int ni = 0; ni < 4; ni++)
        bfr[ni] = *(const bf16x8*)((const char*)lB +
                                   (wn + ni * 16 + (l & 15)) * 128 + kc * 64 + (l >> 4) * 16);
#pragma unroll
      for (int mi = 0; mi < 4; mi++)
#pragma unroll
        for (int ni = 0; ni < 4; ni++)
          acc[mi][ni] = __builtin_amdgcn_mfma_f32_16x16x32_bf16(af[mi], bfr[ni], acc[mi][ni], 0, 0, 0);
    }
  }
  // epilogue: C row = (l>>4)*4 + r, col = l&15 (verified m89/m91 layout)
#pragma unroll
  for (int mi = 0; mi < 4; mi++) {
    int mrow = m0 + wm + mi * 16 + (l >> 4) * 4;
#pragma unroll
    for (int ni = 0; ni < 4; ni++) {
      int ncol = n0 + wn + ni * 16 + (l & 15);
#pragma unroll
      for (int r = 0; r < 4; r++) {
        if constexpr (WF32)
          Cf[(size_t)(mrow + r) * Dm + ncol] = acc[mi][ni][r];
        else
          Cb[(size_t)(mrow + r) * Dm + ncol] = f2bf(acc[mi][ni][r]);
      }
    }
  }
}

// ---------------- RoPE in-place on Q,K [4096][4096] bf16 ----------------
__global__ __launch_bounds__(256) void rope_apply(unsigned short* __restrict__ Q,
                                                  unsigned short* __restrict__ Kt,
                                                  const float* __restrict__ cosT,
                                                  const float* __restrict__ sinT) {
  int idx = blockIdx.x * 256 + threadIdx.x;  // 1,048,576 threads
  unsigned short* P = blockIdx.y ? Kt : Q;
  int j = idx & 7;
  int h = (idx >> 3) & 31;
  int m = idx >> 8;
  int s = m & (Sq - 1);
  size_t base = (size_t)m * Dm + h * HDd + j * 8;
  ushort8v u1 = *(ushort8v*)(P + base);
  ushort8v u2 = *(ushort8v*)(P + base + 64);
  const float* cp = cosT + s * 64 + j * 8;
  const float* sp = sinT + s * 64 + j * 8;
  ushort8v o1, o2;
#pragma unroll
  for (int e = 0; e < 8; e++) {
    float c = cp[e], sn = sp[e];
    float x1 = bf2f(u1[e]), x2 = bf2f(u2[e]);
    o1[e] = f2bf(x1 * c - x2 * sn);
    o2[e] = f2bf(x2 * c + x1 * sn);
  }
  *(ushort8v*)(P + base) = o1;
  *(ushort8v*)(P + base + 64) = o2;
}

// ---------------- V [m][4096] -> VT [(b*H+h)*128 + hd][2048] ----------------
__global__ __launch_bounds__(256) void transpose_v(const unsigned short* __restrict__ V,
                                                   unsigned short* __restrict__ VT) {
  __shared__ unsigned short t[32][33];
  int bh = blockIdx.z;
  int s0 = blockIdx.x * 32, d0 = blockIdx.y * 32;
  int tx = threadIdx.x, ty = threadIdx.y;  // (32,8)
  int b = bh >> 5, h = bh & 31;
#pragma unroll
  for (int i = 0; i < 4; i++) {
    int row = ty + i * 8;
    t[row][tx] = V[((size_t)(b * Sq + s0 + row)) * Dm + h * HDd + d0 + tx];
  }
  __syncthreads();
#pragma unroll
  for (int i = 0; i < 4; i++) {
    int row = ty + i * 8;
    VT[((size_t)bh * HDd + d0 + row) * Sq + s0 + tx] = t[tx][row];
  }
}

// ---------------- flash attention, causal, QB=128 KVB=64, 8 waves ----------
// T14 async-STAGE: issue next tile's K/V global loads into regs BEFORE the
// compute phase; ds_write them after the barrier. Reversed blockIdx.x so
// heavy causal blocks dispatch first.
__global__ __launch_bounds__(512) void flash_attn(const unsigned short* __restrict__ Qg,
                                                  const unsigned short* __restrict__ Kg,
                                                  const unsigned short* __restrict__ VTg,
                                                  unsigned short* __restrict__ Ctx) {
  constexpr int PP = 72;  // P LDS pitch in shorts (144B rows: 4-bank row spread)
  __shared__ unsigned short lK[64 * 128];   // [64 kv][128 hd], XOR-swizzled
  __shared__ unsigned short lV[128 * 64];   // [128 hd][64 kv] (V^T), swizzled
  __shared__ unsigned short lP[8][16 * PP]; // per-wave P tile
  const int tid = threadIdx.x, l = tid & 63, w = tid >> 6;
  const int qb = gridDim.x - 1 - blockIdx.x;  // heavy blocks first
  const int q0 = qb * 128;
  const int bh = blockIdx.y, b = bh >> 5, h = bh & 31;
  const int ntile = 2 * qb + 2;

  // Q fragments: row = l&15, k = (l>>4)*8 + c*32 .. +8
  bf16x8 qf[4];
  {
    int qrow = q0 + w * 16 + (l & 15);
    const unsigned short* qp = Qg + ((size_t)(b * Sq + qrow)) * Dm + h * HDd + (l >> 4) * 8;
#pragma unroll
    for (int c = 0; c < 4; c++) qf[c] = *(const bf16x8*)(qp + c * 32);
  }

  f32x4 acc[8] = {};
  float mrun[4] = {-1e30f, -1e30f, -1e30f, -1e30f};
  float lrun[4] = {0.f, 0.f, 0.f, 0.f};
  const float scale = 0.08838834764831845f;  // 1/sqrt(128)
  const float L2E = 1.4426950408889634f;

  // staging geometry (512 threads)
  const int kr0 = tid >> 4;            // K rows: kr0, kr0+32
  const int kcb = (tid & 15) * 16;
  const int vr0 = tid >> 3;            // V rows: vr0, vr0+64
  const int vcb = (tid & 7) * 16;
  const char* Kbase = (const char*)Kg + ((size_t)(b * Sq) * Dm + h * HDd) * 2;
  const char* Vbase = (const char*)VTg + ((size_t)bh * HDd) * Sq * 2;
  uint4 kreg0, kreg1, vreg0, vreg1;

  auto LOADT = [&](int kv0) {
    kreg0 = *(const uint4*)(Kbase + (size_t)(kv0 + kr0) * (Dm * 2) + kcb);
    kreg1 = *(const uint4*)(Kbase + (size_t)(kv0 + kr0 + 32) * (Dm * 2) + kcb);
    vreg0 = *(const uint4*)(Vbase + (size_t)vr0 * (Sq * 2) + kv0 * 2 + vcb);
    vreg1 = *(const uint4*)(Vbase + (size_t)(vr0 + 64) * (Sq * 2) + kv0 * 2 + vcb);
  };
  auto STORET = [&]() {
    int ks = kcb ^ ((kr0 & 7) << 4);   // (kr0+32)&7 == kr0&7
    int vs = vcb ^ ((vr0 & 7) << 4);
    *(uint4*)((char*)lK + kr0 * 256 + ks) = kreg0;
    *(uint4*)((char*)lK + (kr0 + 32) * 256 + ks) = kreg1;
    *(uint4*)((char*)lV + vr0 * 128 + vs) = vreg0;
    *(uint4*)((char*)lV + (vr0 + 64) * 128 + vs) = vreg1;
  };

  LOADT(0);
  STORET();
  __syncthreads();

  for (int t = 0; t < ntile; t++) {
    const int kv0 = t * 64;
    if (t + 1 < ntile) LOADT((t + 1) * 64);  // in flight during compute

    // QK^T: scores[16q x 64kv] per wave
    f32x4 sc[4] = {};
    __builtin_amdgcn_s_setprio(1);
#pragma unroll
    for (int nb = 0; nb < 4; nb++) {
      int kvr = nb * 16 + (l & 15);
#pragma unroll
      for (int c = 0; c < 4; c++) {
        int cb = (c * 64 + (l >> 4) * 16) ^ ((kvr & 7) << 4);
        bf16x8 kf = *(const bf16x8*)((const char*)lK + kvr * 256 + cb);
        sc[nb] = __builtin_amdgcn_mfma_f32_16x16x32_bf16(qf[c], kf, sc[nb], 0, 0, 0);
      }
    }
    __builtin_amdgcn_s_setprio(0);

    // scale (+ causal mask only on the two diagonal-adjacent tiles)
    float sv[4][4];
    const bool domask = (t >= ntile - 2);
#pragma unroll
    for (int nb = 0; nb < 4; nb++) {
      int kvg = kv0 + nb * 16 + (l & 15);
#pragma unroll
      for (int r = 0; r < 4; r++) {
        float vv = sc[nb][r] * scale;
        if (domask) {
          int qg = q0 + w * 16 + (l >> 4) * 4 + r;
          vv = (kvg <= qg) ? vv : -1e30f;
        }
        sv[nb][r] = vv;
      }
    }
    // row max over the 16 col-lanes (same l>>4 group)
    float rmax[4];
#pragma unroll
    for (int r = 0; r < 4; r++)
      rmax[r] = fmaxf(fmaxf(sv[0][r], sv[1][r]), fmaxf(sv[2][r], sv[3][r]));
#pragma unroll
    for (int d = 1; d < 16; d <<= 1)
#pragma unroll
      for (int r = 0; r < 4; r++) rmax[r] = fmaxf(rmax[r], __shfl_xor(rmax[r], d, 64));

    float mnew[4], alpha[4], psum[4];
#pragma unroll
    for (int r = 0; r < 4; r++) {
      mnew[r] = fmaxf(mrun[r], rmax[r]);
      alpha[r] = exp2f((mrun[r] - mnew[r]) * L2E);
      psum[r] = 0.f;
    }
#pragma unroll
    for (int nb = 0; nb < 4; nb++)
#pragma unroll
      for (int r = 0; r < 4; r++) {
        float pe = exp2f((sv[nb][r] - mnew[r]) * L2E);
        sv[nb][r] = pe;
        psum[r] += pe;
      }
#pragma unroll
    for (int d = 1; d < 16; d <<= 1)
#pragma unroll
      for (int r = 0; r < 4; r++) psum[r] += __shfl_xor(psum[r], d, 64);
#pragma unroll
    for (int r = 0; r < 4; r++) {
      lrun[r] = lrun[r] * alpha[r] + psum[r];
      mrun[r] = mnew[r];
    }
#pragma unroll
    for (int hdnb = 0; hdnb < 8; hdnb++)
#pragma unroll
      for (int r = 0; r < 4; r++) acc[hdnb][r] *= alpha[r];

    // P -> per-wave LDS tile [16][PP]
    unsigned short* P = lP[w];
#pragma unroll
    for (int nb = 0; nb < 4; nb++)
#pragma unroll
      for (int r = 0; r < 4; r++)
        P[((l >> 4) * 4 + r) * PP + nb * 16 + (l & 15)] = f2bf(sv[nb][r]);

    // PV: A = P[16q x 64kv], B = V[64kv x 128hd] from swizzled V^T LDS
    bf16x8 pf[2];
#pragma unroll
    for (int kc = 0; kc < 2; kc++)
      pf[kc] = *(const bf16x8*)(P + (l & 15) * PP + kc * 32 + (l >> 4) * 8);
    __builtin_amdgcn_s_setprio(1);
#pragma unroll
    for (int hdnb = 0; hdnb < 8; hdnb++) {
      int hdr = hdnb * 16 + (l & 15);
#pragma unroll
      for (int kc = 0; kc < 2; kc++) {
        int cb = (kc * 64 + (l >> 4) * 16) ^ ((hdr & 7) << 4);
        bf16x8 vf = *(const bf16x8*)((const char*)lV + hdr * 128 + cb);
        acc[hdnb] = __builtin_amdgcn_mfma_f32_16x16x32_bf16(pf[kc], vf, acc[hdnb], 0, 0, 0);
      }
    }
    __builtin_amdgcn_s_setprio(0);

    __syncthreads();                    // all waves done reading LDS(t)
    if (t + 1 < ntile) STORET();        // vmcnt auto-waited; write tile t+1
    __syncthreads();                    // LDS(t+1) ready
  }

  // epilogue: ctx[m][h*128+hd] bf16
  float invl[4];
#pragma unroll
  for (int r = 0; r < 4; r++) invl[r] = 1.0f / lrun[r];
#pragma unroll
  for (int hdnb = 0; hdnb < 8; hdnb++)
#pragma unroll
    for (int r = 0; r < 4; r++) {
      size_t mrow = (size_t)(b * Sq + q0 + w * 16 + (l >> 4) * 4 + r);
      Ctx[mrow * Dm + h * HDd + hdnb * 16 + (l & 15)] = f2bf(acc[hdnb][r] * invl[r]);
    }
}

// ---------------- launch ----------------
extern "C" void kernel_launch(void* const* d_in, const int* in_sizes, int n_in,
                              void* d_out, int out_size, void* d_ws, size_t ws_size,
                              hipStream_t stream) {
  (void)in_sizes; (void)n_in; (void)out_size; (void)ws_size;
  const float* x  = (const float*)d_in[0];
  // d_in[1] = mask (causal tril) — hardcoded in flash kernel
  const float* Wq = (const float*)d_in[2];
  const float* Wk = (const float*)d_in[3];
  const float* Wv = (const float*)d_in[4];
  const float* Wo = (const float*)d_in[5];
  float* out = (float*)d_out;

  char* p = (char*)d_ws;
  const size_t TB = (size_t)Dm * Dm * 2;  // 32 MiB per bf16 4096x4096 tensor
  unsigned short* xb = (unsigned short*)p; p += TB;  // also reused as VT
  unsigned short* wq = (unsigned short*)p; p += TB;
  unsigned short* wk = (unsigned short*)p; p += TB;
  unsigned short* wv = (unsigned short*)p; p += TB;
  unsigned short* wo = (unsigned short*)p; p += TB;
  unsigned short* qb = (unsigned short*)p; p += TB;
  unsigned short* kb = (unsigned short*)p; p += TB;
  unsigned short* vb = (unsigned short*)p; p += TB;  // also reused as ctx
  float* cosT = (float*)p; p += (size_t)Sq * 64 * 4;
  float* sinT = (float*)p; p += (size_t)Sq * 64 * 4;
  unsigned short* vT  = xb;  // x bf16 dead after the 3 projection GEMMs
  unsigned short* ctx = vb;  // v bf16 dead after transpose

  const int n8 = Dm * Dm / 8;      // 2,097,152
  const int castBlocks = n8 / 256; // 8192

  cast_f32_bf16<<<castBlocks, 256, 0, stream>>>(x, xb, n8);
  cast_f32_bf16<<<castBlocks, 256, 0, stream>>>(Wq, wq, n8);
  cast_f32_bf16<<<castBlocks, 256, 0, stream>>>(Wk, wk, n8);
  cast_f32_bf16<<<castBlocks, 256, 0, stream>>>(Wv, wv, n8);
  cast_f32_bf16<<<castBlocks, 256, 0, stream>>>(Wo, wo, n8);
  rope_tables<<<512, 256, 0, stream>>>(cosT, sinT);

  dim3 gg(32, 32);
  gemm_nt<0><<<gg, 256, 0, stream>>>(xb, wq, qb, nullptr, Dm);
  gemm_nt<0><<<gg, 256, 0, stream>>>(xb, wk, kb, nullptr, Dm);
  gemm_nt<0><<<gg, 256, 0, stream>>>(xb, wv, vb, nullptr, Dm);

  rope_apply<<<dim3(4096, 2), 256, 0, stream>>>(qb, kb, cosT, sinT);
  transpose_v<<<dim3(64, 4, 64), dim3(32, 8), 0, stream>>>(vb, vT);

  flash_attn<<<dim3(Sq / 128, Bb * Hh), 512, 0, stream>>>(qb, kb, vT, ctx);

  gemm_nt<1><<<gg, 256, 0, stream>>>(ctx, wo, nullptr, out, Dm);
}

// Round 4
// 1373.870 us; speedup vs baseline: 1.1368x; 1.1263x over previous
//
#include <hip/hip_runtime.h>

// ---------------- types / helpers ----------------
typedef __bf16 bf16x8 __attribute__((ext_vector_type(8)));
typedef float  f32x4  __attribute__((ext_vector_type(4)));
typedef unsigned short ushort8v __attribute__((ext_vector_type(8)));

#define DEV __device__ __forceinline__

constexpr int Dm = 4096;   // model dim
constexpr int Sq = 2048;   // seq len
constexpr int Bb = 2;      // batch
constexpr int Hh = 32;     // heads
constexpr int HDd = 128;   // head dim

DEV unsigned short f2bf(float f) {
  __bf16 h = (__bf16)f;                   // native RNE convert (v_cvt_*_bf16)
  union { __bf16 h; unsigned short u; } v; v.h = h;
  return v.u;
}
DEV float bf2f(unsigned short s) {
  union { unsigned u; float f; } v; v.u = ((unsigned)s) << 16;
  return v.f;
}

// ---------------- cast fp32 -> bf16, 8 elems/thread ----------------
__global__ __launch_bounds__(256) void cast_f32_bf16(const float* __restrict__ src,
                                                     unsigned short* __restrict__ dst,
                                                     int n8) {
  int i = blockIdx.x * 256 + threadIdx.x;
  if (i >= n8) return;
  const float4* s4 = (const float4*)src;
  float4 a = s4[2 * i], b = s4[2 * i + 1];
  ushort8v o;
  o[0] = f2bf(a.x); o[1] = f2bf(a.y); o[2] = f2bf(a.z); o[3] = f2bf(a.w);
  o[4] = f2bf(b.x); o[5] = f2bf(b.y); o[6] = f2bf(b.z); o[7] = f2bf(b.w);
  *(ushort8v*)(dst + 8 * i) = o;
}

// ---------------- RoPE cos/sin tables [S][64] ----------------
__global__ __launch_bounds__(256) void rope_tables(float* __restrict__ cosT,
                                                   float* __restrict__ sinT) {
  int idx = blockIdx.x * 256 + threadIdx.x;  // S*64 = 131072
  int s = idx >> 6, i = idx & 63;
  float inv = expf(-(float)i * (9.210340371976184f / 64.0f));
  float f = (float)s * inv;
  cosT[idx] = cosf(f);
  sinT[idx] = sinf(f);
}

// ---------------- GEMM C[m,n] = sum_k A[m,k]*B[n,k]  (m97 structure) ------
// UNCHANGED from round 3 (isolating the flash/transpose changes).
template <int WF32>
__global__ __launch_bounds__(256) void gemm_nt(const unsigned short* __restrict__ A,
                                               const unsigned short* __restrict__ Bw,
                                               unsigned short* __restrict__ Cb,
                                               float* __restrict__ Cf, int K) {
  constexpr int TM = 128, BK = 64;
  __shared__ unsigned short lA[TM * BK];
  __shared__ unsigned short lB[TM * BK];
  const int tid = threadIdx.x;
  const int l = tid & 63, w = tid >> 6;
  const int wm = (w >> 1) * 64, wn = (w & 1) * 64;
  const int m0 = blockIdx.x * TM, n0 = blockIdx.y * TM;
  f32x4 acc[4][4] = {};

  const unsigned short* Ag = A + (size_t)m0 * K;
  const unsigned short* Bg = Bw + (size_t)n0 * K;
  const int srow = l >> 3;
  const int scb = (l & 7) * 16;

  for (int k0 = 0; k0 < K; k0 += BK) {
    __syncthreads();
#pragma unroll
    for (int i = 0; i < 4; i++) {
      int row = w * 32 + i * 8 + srow;
      __builtin_amdgcn_global_load_lds(
          (const __attribute__((address_space(1))) void*)((const char*)Ag +
              ((size_t)row * K + k0) * 2 + scb),
          (__attribute__((address_space(3))) void*)(lA + (w * 4 + i) * 512),
          16, 0, 0);
      __builtin_amdgcn_global_load_lds(
          (const __attribute__((address_space(1))) void*)((const char*)Bg +
              ((size_t)row * K + k0) * 2 + scb),
          (__attribute__((address_space(3))) void*)(lB + (w * 4 + i) * 512),
          16, 0, 0);
    }
    __syncthreads();
#pragma unroll
    for (int kc = 0; kc < 2; kc++) {
      bf16x8 af[4], bfr[4];
#pragma unroll
      for (int mi = 0; mi < 4; mi++)
        af[mi] = *(const bf16x8*)((const char*)lA +
                                  (wm + mi * 16 + (l & 15)) * 128 + kc * 64 + (l >> 4) * 16);
#pragma unroll
      for (int ni = 0; ni < 4; ni++)
        bfr[ni] = *(const bf16x8*)((const char*)lB +
                                   (wn + ni * 16 + (l & 15)) * 128 + kc * 64 + (l >> 4) * 16);
#pragma unroll
      for (int mi = 0; mi < 4; mi++)
#pragma unroll
        for (int ni = 0; ni < 4; ni++)
          acc[mi][ni] = __builtin_amdgcn_mfma_f32_16x16x32_bf16(af[mi], bfr[ni], acc[mi][ni], 0, 0, 0);
    }
  }
#pragma unroll
  for (int mi = 0; mi < 4; mi++) {
    int mrow = m0 + wm + mi * 16 + (l >> 4) * 4;
#pragma unroll
    for (int ni = 0; ni < 4; ni++) {
      int ncol = n0 + wn + ni * 16 + (l & 15);
#pragma unroll
      for (int r = 0; r < 4; r++) {
        if constexpr (WF32)
          Cf[(size_t)(mrow + r) * Dm + ncol] = acc[mi][ni][r];
        else
          Cb[(size_t)(mrow + r) * Dm + ncol] = f2bf(acc[mi][ni][r]);
      }
    }
  }
}

// ---------------- RoPE in-place on Q,K [4096][4096] bf16 ----------------
__global__ __launch_bounds__(256) void rope_apply(unsigned short* __restrict__ Q,
                                                  unsigned short* __restrict__ Kt,
                                                  const float* __restrict__ cosT,
                                                  const float* __restrict__ sinT) {
  int idx = blockIdx.x * 256 + threadIdx.x;
  unsigned short* P = blockIdx.y ? Kt : Q;
  int j = idx & 7;
  int h = (idx >> 3) & 31;
  int m = idx >> 8;
  int s = m & (Sq - 1);
  size_t base = (size_t)m * Dm + h * HDd + j * 8;
  ushort8v u1 = *(ushort8v*)(P + base);
  ushort8v u2 = *(ushort8v*)(P + base + 64);
  const float* cp = cosT + s * 64 + j * 8;
  const float* sp = sinT + s * 64 + j * 8;
  ushort8v o1, o2;
#pragma unroll
  for (int e = 0; e < 8; e++) {
    float c = cp[e], sn = sp[e];
    float x1 = bf2f(u1[e]), x2 = bf2f(u2[e]);
    o1[e] = f2bf(x1 * c - x2 * sn);
    o2[e] = f2bf(x2 * c + x1 * sn);
  }
  *(ushort8v*)(P + base) = o1;
  *(ushort8v*)(P + base + 64) = o2;
}

// ---------------- V [m][4096] -> VT [(b*H+h)*128+hd][2048], vectorized ----
__global__ __launch_bounds__(256) void transpose_v(const unsigned short* __restrict__ V,
                                                   unsigned short* __restrict__ VT) {
  __shared__ unsigned short t[64][130];  // 260B row stride -> 4-way max on gather
  const int tid = threadIdx.x;
  const int s0 = blockIdx.x * 64;        // 32 tiles
  const int bh = blockIdx.y;             // 64
  const int b = bh >> 5, h = bh & 31;
  const int lhd = (tid & 15) * 8, ls = tid >> 4;
#pragma unroll
  for (int i = 0; i < 4; i++) {
    int s = ls + i * 16;
    ushort8v v = *(const ushort8v*)(V + ((size_t)(b * Sq + s0 + s)) * Dm + h * HDd + lhd);
    *(ushort8v*)&t[s][lhd] = v;
  }
  __syncthreads();
  const int osc = (tid & 7) * 8, ohd = tid >> 3;
#pragma unroll
  for (int j = 0; j < 4; j++) {
    int hd = ohd + j * 32;
    ushort8v o;
#pragma unroll
    for (int e = 0; e < 8; e++) o[e] = t[osc + e][hd];
    *(ushort8v*)(VT + ((size_t)(bh * HDd + hd)) * Sq + s0 + osc) = o;
  }
}

// ---------------- flash attention: QB=128, KVB=64, 8 waves, dbuf LDS -------
// One barrier per tile-step (STORET writes buf^1 while compute reads buf).
// Paired q-tiles (qb, 15-qb) -> every block exactly 34 tile-steps.
// T13 defer-max; scale*log2e folded; swizzled per-wave P tile.
__global__ __launch_bounds__(512, 4) void flash_attn(const unsigned short* __restrict__ Qg,
                                                     const unsigned short* __restrict__ Kg,
                                                     const unsigned short* __restrict__ VTg,
                                                     unsigned short* __restrict__ Ctx) {
  __shared__ unsigned short lK[2][64 * 128];   // [64 kv][128 hd] swizzled, x2
  __shared__ unsigned short lV[2][128 * 64];   // [128 hd][64 kv] swizzled, x2
  __shared__ unsigned short lP[8][16 * 64];    // per-wave P, XOR-swizzled rows
  const int tid = threadIdx.x, l = tid & 63, w = tid >> 6;
  const int bx = blockIdx.x;                   // [0,8)
  const int bh = blockIdx.y, b = bh >> 5, h = bh & 31;

  const float SC = 0.12755102331353136f;       // (1/sqrt(128)) * log2(e)
  const float THR = 11.541560327111707f;       // 8 * log2(e)

  // staging geometry (512 threads)
  const int kr0 = tid >> 4;            // K rows: kr0, kr0+32
  const int kcb = (tid & 15) * 16;
  const int vr0 = tid >> 3;            // V rows: vr0, vr0+64
  const int vcb = (tid & 7) * 16;
  const char* Kbase = (const char*)Kg + ((size_t)(b * Sq) * Dm + h * HDd) * 2;
  const char* Vbase = (const char*)VTg + ((size_t)bh * HDd) * Sq * 2;
  uint4 kreg0, kreg1, vreg0, vreg1;
  const int ks = kcb ^ ((kr0 & 7) << 4);
  const int vs = vcb ^ ((vr0 & 7) << 4);

  auto LOADT = [&](int kv0) {
    kreg0 = *(const uint4*)(Kbase + (size_t)(kv0 + kr0) * (Dm * 2) + kcb);
    kreg1 = *(const uint4*)(Kbase + (size_t)(kv0 + kr0 + 32) * (Dm * 2) + kcb);
    vreg0 = *(const uint4*)(Vbase + (size_t)vr0 * (Sq * 2) + kv0 * 2 + vcb);
    vreg1 = *(const uint4*)(Vbase + (size_t)(vr0 + 64) * (Sq * 2) + kv0 * 2 + vcb);
  };
  auto STORET = [&](int buf) {
    *(uint4*)((char*)lK[buf] + kr0 * 256 + ks) = kreg0;
    *(uint4*)((char*)lK[buf] + (kr0 + 32) * 256 + ks) = kreg1;
    *(uint4*)((char*)lV[buf] + vr0 * 128 + vs) = vreg0;
    *(uint4*)((char*)lV[buf] + (vr0 + 64) * 128 + vs) = vreg1;
  };

  for (int part = 0; part < 2; ++part) {
    const int qb = part ? bx : (15 - bx);      // heavy half first
    const int q0 = qb * 128;
    const int ntile = 2 * qb + 2;

    // Q fragments: row = l&15, k = (l>>4)*8 + c*32 .. +8
    bf16x8 qf[4];
    {
      int qrow = q0 + w * 16 + (l & 15);
      const unsigned short* qp = Qg + ((size_t)(b * Sq + qrow)) * Dm + h * HDd + (l >> 4) * 8;
#pragma unroll
      for (int c = 0; c < 4; c++) qf[c] = *(const bf16x8*)(qp + c * 32);
    }

    f32x4 acc[8] = {};
    float mrun[4] = {-1e30f, -1e30f, -1e30f, -1e30f};
    float lrun[4] = {0.f, 0.f, 0.f, 0.f};

    // prologue: fill buf0 with tile0, issue tile1 loads
    LOADT(0);
    STORET(0);
    if (ntile > 1) LOADT(64);
    __syncthreads();

    int cur = 0;
    for (int t = 0; t < ntile; t++) {
      if (t + 1 < ntile) STORET(cur ^ 1);        // regs from prev iter; other buf
      if (t + 2 < ntile) LOADT((t + 2) * 64);    // in flight for ~2 steps

      const char* Kl = (const char*)lK[cur];
      const char* Vl = (const char*)lV[cur];
      const int kv0 = t * 64;

      // QK^T: sc[nb][r] = S[q=(l>>4)*4+r][kv=nb*16+(l&15)] (pre-scaled later)
      f32x4 sc[4] = {};
      __builtin_amdgcn_s_setprio(1);
#pragma unroll
      for (int nb = 0; nb < 4; nb++) {
        int kvr = nb * 16 + (l & 15);
#pragma unroll
        for (int c = 0; c < 4; c++) {
          int cb = (c * 64 + (l >> 4) * 16) ^ ((kvr & 7) << 4);
          bf16x8 kf = *(const bf16x8*)(Kl + kvr * 256 + cb);
          sc[nb] = __builtin_amdgcn_mfma_f32_16x16x32_bf16(qf[c], kf, sc[nb], 0, 0, 0);
        }
      }
      __builtin_amdgcn_s_setprio(0);

      // scale into log2-space (+ causal mask on the two diagonal tiles)
      const bool domask = (t >= ntile - 2);
#pragma unroll
      for (int nb = 0; nb < 4; nb++) {
        int kvg = kv0 + nb * 16 + (l & 15);
#pragma unroll
        for (int r = 0; r < 4; r++) {
          float vv = sc[nb][r] * SC;
          if (domask) {
            int qg = q0 + w * 16 + (l >> 4) * 4 + r;
            vv = (kvg <= qg) ? vv : -1e30f;
          }
          sc[nb][r] = vv;
        }
      }
      // row max over 16 col-lanes
      float rmax[4];
#pragma unroll
      for (int r = 0; r < 4; r++)
        rmax[r] = fmaxf(fmaxf(sc[0][r], sc[1][r]), fmaxf(sc[2][r], sc[3][r]));
#pragma unroll
      for (int d = 1; d < 16; d <<= 1)
#pragma unroll
        for (int r = 0; r < 4; r++) rmax[r] = fmaxf(rmax[r], __shfl_xor(rmax[r], d, 64));

      // T13 defer-max: only rescale when max grew by > THR (log2 space)
      bool defer = __all((rmax[0] - mrun[0] <= THR) & (rmax[1] - mrun[1] <= THR) &
                         (rmax[2] - mrun[2] <= THR) & (rmax[3] - mrun[3] <= THR));
      if (!defer) {
        float alpha[4];
#pragma unroll
        for (int r = 0; r < 4; r++) {
          float mnew = fmaxf(mrun[r], rmax[r]);
          alpha[r] = exp2f(mrun[r] - mnew);
          mrun[r] = mnew;
        }
#pragma unroll
        for (int hdnb = 0; hdnb < 8; hdnb++)
#pragma unroll
          for (int r = 0; r < 4; r++) acc[hdnb][r] *= alpha[r];
#pragma unroll
        for (int r = 0; r < 4; r++) lrun[r] *= alpha[r];
      }

      float psum[4] = {0.f, 0.f, 0.f, 0.f};
#pragma unroll
      for (int nb = 0; nb < 4; nb++)
#pragma unroll
        for (int r = 0; r < 4; r++) {
          float pe = exp2f(sc[nb][r] - mrun[r]);
          sc[nb][r] = pe;
          psum[r] += pe;
        }
#pragma unroll
      for (int d = 1; d < 16; d <<= 1)
#pragma unroll
        for (int r = 0; r < 4; r++) psum[r] += __shfl_xor(psum[r], d, 64);
#pragma unroll
      for (int r = 0; r < 4; r++) lrun[r] += psum[r];

      // P -> per-wave swizzled LDS tile [16 q][64 kv]
      char* P = (char*)lP[w];
#pragma unroll
      for (int nb = 0; nb < 4; nb++)
#pragma unroll
        for (int r = 0; r < 4; r++) {
          int prow = (l >> 4) * 4 + r;
          int pb = (prow * 128 + nb * 32 + (l & 15) * 2) ^ ((prow & 7) << 4);
          *(unsigned short*)(P + pb) = f2bf(sc[nb][r]);
        }

      // PV: A = P[16q x 64kv], B = V^T LDS [128hd][64kv]
      bf16x8 pf[2];
#pragma unroll
      for (int kc = 0; kc < 2; kc++) {
        int row = l & 15;
        int pb = row * 128 + ((kc * 64 + (l >> 4) * 16) ^ ((row & 7) << 4));
        pf[kc] = *(const bf16x8*)(P + pb);
      }
      __builtin_amdgcn_s_setprio(1);
#pragma unroll
      for (int hdnb = 0; hdnb < 8; hdnb++) {
        int hdr = hdnb * 16 + (l & 15);
#pragma unroll
        for (int kc = 0; kc < 2; kc++) {
          int cb = (kc * 64 + (l >> 4) * 16) ^ ((hdr & 7) << 4);
          bf16x8 vf = *(const bf16x8*)(Vl + hdr * 128 + cb);
          acc[hdnb] = __builtin_amdgcn_mfma_f32_16x16x32_bf16(pf[kc], vf, acc[hdnb], 0, 0, 0);
        }
      }
      __builtin_amdgcn_s_setprio(0);

      __syncthreads();   // single barrier: buf^1 writes done, buf reads done
      cur ^= 1;
    }

    // epilogue: ctx[m][h*128+hd] bf16
    float invl[4];
#pragma unroll
    for (int r = 0; r < 4; r++) invl[r] = 1.0f / lrun[r];
#pragma unroll
    for (int hdnb = 0; hdnb < 8; hdnb++)
#pragma unroll
      for (int r = 0; r < 4; r++) {
        size_t mrow = (size_t)(b * Sq + q0 + w * 16 + (l >> 4) * 4 + r);
        Ctx[mrow * Dm + h * HDd + hdnb * 16 + (l & 15)] = f2bf(acc[hdnb][r] * invl[r]);
      }
  }
}

// ---------------- launch ----------------
extern "C" void kernel_launch(void* const* d_in, const int* in_sizes, int n_in,
                              void* d_out, int out_size, void* d_ws, size_t ws_size,
                              hipStream_t stream) {
  (void)in_sizes; (void)n_in; (void)out_size; (void)ws_size;
  const float* x  = (const float*)d_in[0];
  // d_in[1] = mask (causal tril) — hardcoded in flash kernel
  const float* Wq = (const float*)d_in[2];
  const float* Wk = (const float*)d_in[3];
  const float* Wv = (const float*)d_in[4];
  const float* Wo = (const float*)d_in[5];
  float* out = (float*)d_out;

  char* p = (char*)d_ws;
  const size_t TB = (size_t)Dm * Dm * 2;  // 32 MiB per bf16 4096x4096 tensor
  unsigned short* xb = (unsigned short*)p; p += TB;  // also reused as VT
  unsigned short* wq = (unsigned short*)p; p += TB;
  unsigned short* wk = (unsigned short*)p; p += TB;
  unsigned short* wv = (unsigned short*)p; p += TB;
  unsigned short* wo = (unsigned short*)p; p += TB;
  unsigned short* qb = (unsigned short*)p; p += TB;
  unsigned short* kb = (unsigned short*)p; p += TB;
  unsigned short* vb = (unsigned short*)p; p += TB;  // also reused as ctx
  float* cosT = (float*)p; p += (size_t)Sq * 64 * 4;
  float* sinT = (float*)p; p += (size_t)Sq * 64 * 4;
  unsigned short* vT  = xb;  // x bf16 dead after the 3 projection GEMMs
  unsigned short* ctx = vb;  // v bf16 dead after transpose

  const int n8 = Dm * Dm / 8;
  const int castBlocks = n8 / 256;

  cast_f32_bf16<<<castBlocks, 256, 0, stream>>>(x, xb, n8);
  cast_f32_bf16<<<castBlocks, 256, 0, stream>>>(Wq, wq, n8);
  cast_f32_bf16<<<castBlocks, 256, 0, stream>>>(Wk, wk, n8);
  cast_f32_bf16<<<castBlocks, 256, 0, stream>>>(Wv, wv, n8);
  cast_f32_bf16<<<castBlocks, 256, 0, stream>>>(Wo, wo, n8);
  rope_tables<<<512, 256, 0, stream>>>(cosT, sinT);

  dim3 gg(32, 32);
  gemm_nt<0><<<gg, 256, 0, stream>>>(xb, wq, qb, nullptr, Dm);
  gemm_nt<0><<<gg, 256, 0, stream>>>(xb, wk, kb, nullptr, Dm);
  gemm_nt<0><<<gg, 256, 0, stream>>>(xb, wv, vb, nullptr, Dm);

  rope_apply<<<dim3(4096, 2), 256, 0, stream>>>(qb, kb, cosT, sinT);
  transpose_v<<<dim3(32, 64), 256, 0, stream>>>(vb, vT);

  flash_attn<<<dim3(8, Bb * Hh), 512, 0, stream>>>(qb, kb, vT, ctx);

  gemm_nt<1><<<gg, 256, 0, stream>>>(ctx, wo, nullptr, out, Dm);
}